// Round 1
// baseline (785.105 us; speedup 1.0000x reference)
//
#include <hip/hip_runtime.h>

#define N_VERT 1000000
#define N_EDGE 16000000

// Scatter-add: cbar[dst[e]] += edge_attr[e], vectorized 4 edges/thread.
__global__ void scatter_add_kernel(const int* __restrict__ dst,
                                   const float* __restrict__ ea,
                                   float* __restrict__ cbar,
                                   int n_edges4) {
    int i = blockIdx.x * blockDim.x + threadIdx.x;
    const int stride = gridDim.x * blockDim.x;
    for (; i < n_edges4; i += stride) {
        int4   d = reinterpret_cast<const int4*>(dst)[i];
        float4 v = reinterpret_cast<const float4*>(ea)[i];
        atomicAdd(&cbar[d.x], v.x);
        atomicAdd(&cbar[d.y], v.y);
        atomicAdd(&cbar[d.z], v.z);
        atomicAdd(&cbar[d.w], v.w);
    }
}

// out[i] = {A, b, x + w*(b - cbar)/A}
__global__ void vertex_update_kernel(const float* __restrict__ va,
                                     const float* __restrict__ cbar,
                                     const float* __restrict__ g,
                                     float* __restrict__ out,
                                     int n) {
    int i = blockIdx.x * blockDim.x + threadIdx.x;
    if (i >= n) return;
    float A = va[3 * i + 0];
    float b = va[3 * i + 1];
    float x = va[3 * i + 2];
    float w = g[0];
    float xn = x + w * (b - cbar[i]) / A;
    out[3 * i + 0] = A;
    out[3 * i + 1] = b;
    out[3 * i + 2] = xn;
}

extern "C" void kernel_launch(void* const* d_in, const int* in_sizes, int n_in,
                              void* d_out, int out_size, void* d_ws, size_t ws_size,
                              hipStream_t stream) {
    const float* vertex_attr = (const float*)d_in[0];   // (N,3)
    const int*   edgeij      = (const int*)d_in[1];     // (2, E); row 0 = dst
    const float* edge_attr   = (const float*)d_in[2];   // (E,1)
    const float* g           = (const float*)d_in[3];   // (1,)
    // d_in[4] = batch, unused

    const int n_vert = in_sizes[0] / 3;
    const int n_edge = in_sizes[2];

    float* cbar = (float*)d_ws;                         // n_vert floats

    // Zero the accumulator every call (harness poisons ws once, never restores).
    hipMemsetAsync(cbar, 0, (size_t)n_vert * sizeof(float), stream);

    // Scatter-add over edges (dst = edgeij row 0).
    const int n_edges4 = n_edge / 4;                    // 16M % 4 == 0
    const int sb = 256;
    const int sg = 2048;                                 // grid-stride
    scatter_add_kernel<<<sg, sb, 0, stream>>>(edgeij, edge_attr, cbar, n_edges4);

    // Vertex update.
    const int ub = 256;
    const int ug = (n_vert + ub - 1) / ub;
    vertex_update_kernel<<<ug, ub, 0, stream>>>(vertex_attr, cbar, g,
                                                (float*)d_out, n_vert);
}